// Round 5
// baseline (331.024 us; speedup 1.0000x reference)
//
#include <hip/hip_runtime.h>
#include <hip/hip_bf16.h>

typedef _Float16 f16x8 __attribute__((ext_vector_type(8)));
typedef float f32x4 __attribute__((ext_vector_type(4)));

#define TAU 1e-4f   // margin below which we rescue in exact f32 (~100 sigma of split-fp16 noise)

// ---------------- kernel 1: q[m] = (counts[m] > 0) ? 1/||p_m|| : 0 ; zero worklist count ----------------
__global__ __launch_bounds__(64) void proto_qnorm_kernel(
    const float* __restrict__ P, const int* __restrict__ counts,
    float* __restrict__ q, int* __restrict__ wcount, int M, int Dd) {
  if (blockIdx.x == 0 && threadIdx.x == 0) *wcount = 0;
  int m = blockIdx.x;
  int lane = threadIdx.x;
  float s = 0.f;
  for (int k = lane * 4; k < Dd; k += 256) {
    float4 v = *reinterpret_cast<const float4*>(P + (size_t)m * Dd + k);
    s += v.x * v.x + v.y * v.y + v.z * v.z + v.w * v.w;
  }
  for (int off = 32; off > 0; off >>= 1) s += __shfl_xor(s, off, 64);
  if (lane == 0) q[m] = (counts[m] > 0) ? (1.0f / sqrtf(s)) : 0.0f;
}

// ---------------- kernel 1.5: pre-split B-hat = P*q into packed (hi,lo) fp16 fragments ----------------
// Packed so that MFMA B-fragment (p16, kc) for lane L is bhi[((p16*8+kc)<<6) + L]:
// a fragment load = 64 lanes x contiguous 16B = fully coalesced 1KB from L2.
// Element (m, k): p16=m>>4, c=m&15, kc=k>>5, g=(k&31)>>3 -> slot (p16*8+kc)*64 + g*16 + c.
__global__ __launch_bounds__(256) void prep_kernel(
    const float* __restrict__ P, const float* __restrict__ q,
    f16x8* __restrict__ bhi, f16x8* __restrict__ blo) {
  const int id = blockIdx.x * 256 + threadIdx.x;  // 32768 = 1024 m x 32 k-groups
  const int m = id >> 5, kg = id & 31;
  const float qm = q[m];
  const float nanv = __builtin_nanf("");          // masked protos -> NaN (screened out in fold)
  const float* src = P + (size_t)m * 256 + kg * 8;
  float4 v0 = *reinterpret_cast<const float4*>(src);
  float4 v1 = *reinterpret_cast<const float4*>(src + 4);
  float pe[8] = {v0.x, v0.y, v0.z, v0.w, v1.x, v1.y, v1.z, v1.w};
  f16x8 hi, lo;
#pragma unroll
  for (int t = 0; t < 8; ++t) {
    const float ph = (qm > 0.f) ? pe[t] * qm : nanv;
    const _Float16 h = (_Float16)ph;
    hi[t] = h;
    lo[t] = (_Float16)(ph - (float)h);            // exact residual (Sterbenz), then rounded
  }
  const int dst = ((m >> 4) * 8 + (kg >> 2)) * 64 + (kg & 3) * 16 + (m & 15);
  bhi[dst] = hi;
  blo[dst] = lo;
}

// ---------------- kernel 2: split-fp16 MFMA screen, B from global (L2), barrier-free K-loop ----------------
// Block: 512 threads = 8 waves (2 row-groups x 4 col-groups). BM=128 rows.
// A: E split into (hi,lo) fp16, full K=256, resident in 128KB LDS, XOR-swizzled. ONE stage barrier.
// B: pre-split fragments loaded straight from L2 into VGPRs, one-kc-ahead register prefetch.
// dot accumulated as lo*hi + hi*lo + hi*hi chained in one f32 MFMA accumulator.
__global__ __launch_bounds__(512, 2) void screen_kernel(
    const float* __restrict__ E, const f16x8* __restrict__ bhi,
    const f16x8* __restrict__ blo, int* __restrict__ out,
    int* __restrict__ wcount, int* __restrict__ wl, int wlcap) {
  __shared__ __align__(16) unsigned char ldsA[131072];  // 128 rows x 1024B ([hi 512 | lo 512])

  const int tid = threadIdx.x;
  const int wave = tid >> 6, lane = tid & 63;
  const int rg = wave >> 2, cg = wave & 3;
  const int g = lane >> 4, c = lane & 15;
  const int blockRow = blockIdx.x * 128;

  // ---- stage A once: E[blockRow..+128][0..256) f32 -> (hi,lo) fp16, swizzled ----
  {
    const int row = tid >> 2, qq = tid & 3;  // each thread: 64 consecutive k of one row
    const float* src = E + (size_t)(blockRow + row) * 256 + qq * 64;
    const int rswz = (row & 7) << 4;
#pragma unroll
    for (int o = 0; o < 8; ++o) {
      float4 v0 = *reinterpret_cast<const float4*>(src + o * 8);
      float4 v1 = *reinterpret_cast<const float4*>(src + o * 8 + 4);
      float e[8] = {v0.x, v0.y, v0.z, v0.w, v1.x, v1.y, v1.z, v1.w};
      f16x8 hi, lo;
#pragma unroll
      for (int t = 0; t < 8; ++t) {
        _Float16 h = (_Float16)e[t];
        hi[t] = h;
        lo[t] = (_Float16)(e[t] - (float)h);
      }
      const int base = row * 1024 + (qq * 64 + o * 8) * 2;
      *reinterpret_cast<f16x8*>(ldsA + (base ^ rswz)) = hi;
      *reinterpret_cast<f16x8*>(ldsA + ((base + 512) ^ rswz)) = lo;
    }
  }
  __syncthreads();

  // top-2 state per lane: 16 row-slots (rows = rg*64 + fr*16 + g*4 + reg)
  float v1r[16], v2r[16];
  int i1r[16];
#pragma unroll
  for (int s = 0; s < 16; ++s) { v1r[s] = -INFINITY; v2r[s] = -INFINITY; i1r[s] = 0; }

  const f16x8* bhl = bhi + lane;
  const f16x8* bll = blo + lane;

  // prologue: load B fragments for (pt=0, kc=0)
  f16x8 bhc[4], blc[4];
#pragma unroll
  for (int fc = 0; fc < 4; ++fc) {
    const int fidx = ((cg * 4 + fc) * 8) << 6;   // p16 = 0*16 + cg*4 + fc, kc=0
    bhc[fc] = bhl[fidx];
    blc[fc] = bll[fidx];
  }

  for (int pt = 0; pt < 4; ++pt) {
    f32x4 acc[4][4];
#pragma unroll
    for (int fr = 0; fr < 4; ++fr)
#pragma unroll
      for (int fc = 0; fc < 4; ++fc) acc[fr][fc] = (f32x4){0.f, 0.f, 0.f, 0.f};

#pragma unroll
    for (int kc = 0; kc < 8; ++kc) {
      // ---- prefetch next (pt,kc) B fragments into regs (L2 latency hides under MFMA) ----
      f16x8 bhn[4], bln[4];
      const int t = pt * 8 + kc + 1;
      if (t < 32) {
        const int pn = t >> 3, kn = t & 7;
#pragma unroll
        for (int fc = 0; fc < 4; ++fc) {
          const int fidx = ((pn * 16 + cg * 4 + fc) * 8 + kn) << 6;
          bhn[fc] = bhl[fidx];
          bln[fc] = bll[fidx];
        }
      }
      // ---- A fragments from LDS ----
      f16x8 ah[4], al[4];
#pragma unroll
      for (int fr = 0; fr < 4; ++fr) {
        const int rowA = rg * 64 + fr * 16 + c;
        const int ab = rowA * 1024 + kc * 64 + g * 16;
        const int sw = (rowA & 7) << 4;
        ah[fr] = *reinterpret_cast<const f16x8*>(ldsA + (ab ^ sw));
        al[fr] = *reinterpret_cast<const f16x8*>(ldsA + ((ab + 512) ^ sw));
      }
      // ---- 3-term MFMA ----
#pragma unroll
      for (int fr = 0; fr < 4; ++fr)
#pragma unroll
        for (int fc = 0; fc < 4; ++fc) {
          f32x4 a = acc[fr][fc];
          a = __builtin_amdgcn_mfma_f32_16x16x32_f16(al[fr], bhc[fc], a, 0, 0, 0);
          a = __builtin_amdgcn_mfma_f32_16x16x32_f16(ah[fr], blc[fc], a, 0, 0, 0);
          a = __builtin_amdgcn_mfma_f32_16x16x32_f16(ah[fr], bhc[fc], a, 0, 0, 0);
          acc[fr][fc] = a;
        }
      // ---- rotate prefetch regs ----
#pragma unroll
      for (int fc = 0; fc < 4; ++fc) { bhc[fc] = bhn[fc]; blc[fc] = bln[fc]; }
    }

    // ---- fold this pt's 64 proto-columns into top-2 (full f32, strict > keeps lowest m) ----
#pragma unroll
    for (int fc = 0; fc < 4; ++fc) {
      const int mcol = pt * 256 + cg * 64 + fc * 16 + c;
#pragma unroll
      for (int fr = 0; fr < 4; ++fr)
#pragma unroll
        for (int reg = 0; reg < 4; ++reg) {
          const int s = fr * 4 + reg;
          float v = acc[fr][fc][reg];
          v = (v == v) ? v : -INFINITY;  // NaN guard (masked protos)
          const float nv1 = fmaxf(v1r[s], v);
          v2r[s] = fmaxf(v2r[s], fminf(v1r[s], v));
          i1r[s] = (v > v1r[s]) ? mcol : i1r[s];
          v1r[s] = nv1;
        }
    }
  }

  // ---- cross-lane top-2 merge over the 16 c-lanes sharing each row ----
#pragma unroll
  for (int s = 0; s < 16; ++s) {
#pragma unroll
    for (int off = 1; off <= 8; off <<= 1) {
      const float ov1 = __shfl_xor(v1r[s], off);
      const float ov2 = __shfl_xor(v2r[s], off);
      const int oi1 = __shfl_xor(i1r[s], off);
      const bool take = (ov1 > v1r[s]) || (ov1 == v1r[s] && oi1 < i1r[s]);
      const float nv2 = fmaxf(fmaxf(v2r[s], ov2), fminf(v1r[s], ov1));
      v1r[s] = fmaxf(v1r[s], ov1);
      i1r[s] = take ? oi1 : i1r[s];
      v2r[s] = nv2;
    }
  }

  __syncthreads();  // all waves done with ldsA fragment reads -> reuse for cross-wave merge
  float* mgv1 = reinterpret_cast<float*>(ldsA);          // [128][4]
  float* mgv2 = reinterpret_cast<float*>(ldsA + 2048);   // [128][4]
  int* mgi1 = reinterpret_cast<int*>(ldsA + 4096);       // [128][4]
  if (c == 0) {
#pragma unroll
    for (int s = 0; s < 16; ++s) {
      const int row = rg * 64 + (s >> 2) * 16 + g * 4 + (s & 3);
      mgv1[row * 4 + cg] = v1r[s];
      mgv2[row * 4 + cg] = v2r[s];
      mgi1[row * 4 + cg] = i1r[s];
    }
  }
  __syncthreads();
  if (tid < 128) {
    float v1 = mgv1[tid * 4], v2 = mgv2[tid * 4];
    int i1 = mgi1[tid * 4];
#pragma unroll
    for (int w = 1; w < 4; ++w) {
      const float a1 = mgv1[tid * 4 + w], a2 = mgv2[tid * 4 + w];
      const int ai = mgi1[tid * 4 + w];
      const bool take = (a1 > v1) || (a1 == v1 && ai < i1);
      const float nv2 = fmaxf(fmaxf(v2, a2), fminf(v1, a1));
      v1 = fmaxf(v1, a1);
      i1 = take ? ai : i1;
      v2 = nv2;
    }
    const int grow = blockRow + tid;
    out[grow] = i1;
    const float margin = v1 - v2;
    if (!(margin >= TAU)) {  // NaN-safe: NaN margin -> flagged
      const int p = atomicAdd(wcount, 1);
      if (p < wlcap) wl[p] = grow;
    }
  }
}

// ---------------- kernel 3: exact f32 rescue over the worklist ----------------
// Round-1-identical accumulation per (row, proto): single ascending-k fmaf chain
// (x,y,z,w within each float4), then v = acc*q, ties to the smaller proto index.
__global__ __launch_bounds__(256) void rescue_kernel(
    const float* __restrict__ E, const float* __restrict__ P,
    const float* __restrict__ q, int* __restrict__ out,
    const int* __restrict__ wcount, const int* __restrict__ wl, int wlcap) {
  __shared__ float Elds[8][260];
  __shared__ int rowsS[8];
  __shared__ float wv[8][4];
  __shared__ int wm[8][4];

  const int tid = threadIdx.x;
  const int wave = tid >> 6, lane = tid & 63;
  int total = *wcount;
  if (total > wlcap) total = wlcap;

  for (int b0 = blockIdx.x * 8; b0 < total; b0 += gridDim.x * 8) {
    const int nb = min(8, total - b0);
    __syncthreads();
    if (tid < 8) rowsS[tid] = wl[b0 + (tid < nb ? tid : 0)];
    __syncthreads();
#pragma unroll
    for (int u = 0; u < 2; ++u) {
      const int unit = u * 256 + tid, r = unit >> 6, k4 = unit & 63;
      *reinterpret_cast<float4*>(&Elds[r][k4 * 4]) =
          *reinterpret_cast<const float4*>(E + (size_t)rowsS[r] * 256 + k4 * 4);
    }
    __syncthreads();

    float acc[8][4];  // 8 rows x 4 protos (m = tid + 256*j)
#pragma unroll
    for (int r = 0; r < 8; ++r)
#pragma unroll
      for (int j = 0; j < 4; ++j) acc[r][j] = 0.f;

#pragma unroll 2
    for (int k4 = 0; k4 < 64; ++k4) {
      float4 pv[4];
#pragma unroll
      for (int j = 0; j < 4; ++j)
        pv[j] = *reinterpret_cast<const float4*>(P + (size_t)(tid + 256 * j) * 256 + k4 * 4);
      float4 ev[8];
#pragma unroll
      for (int r = 0; r < 8; ++r) ev[r] = *reinterpret_cast<const float4*>(&Elds[r][k4 * 4]);
#pragma unroll
      for (int r = 0; r < 8; ++r)
#pragma unroll
        for (int j = 0; j < 4; ++j) {
          float a = acc[r][j];
          a = fmaf(pv[j].x, ev[r].x, a);
          a = fmaf(pv[j].y, ev[r].y, a);
          a = fmaf(pv[j].z, ev[r].z, a);
          a = fmaf(pv[j].w, ev[r].w, a);
          acc[r][j] = a;
        }
    }

    float qv[4];
#pragma unroll
    for (int j = 0; j < 4; ++j) qv[j] = q[tid + 256 * j];

#pragma unroll
    for (int r = 0; r < 8; ++r) {
      float bv = -3.0e38f;
      int bm = 0;
#pragma unroll
      for (int j = 0; j < 4; ++j) {  // m ascending -> strict > keeps lowest m
        const float v = (qv[j] > 0.f) ? acc[r][j] * qv[j] : -1.0e30f;
        if (v > bv) { bv = v; bm = tid + 256 * j; }
      }
#pragma unroll
      for (int off = 1; off <= 32; off <<= 1) {
        const float ov = __shfl_xor(bv, off);
        const int om = __shfl_xor(bm, off);
        if (ov > bv || (ov == bv && om < bm)) { bv = ov; bm = om; }
      }
      if (lane == 0) { wv[r][wave] = bv; wm[r][wave] = bm; }
    }
    __syncthreads();
    if (tid < 8) {
      float bv = wv[tid][0];
      int bm = wm[tid][0];
#pragma unroll
      for (int w = 1; w < 4; ++w) {
        const float ov = wv[tid][w];
        const int om = wm[tid][w];
        if (ov > bv || (ov == bv && om < bm)) { bv = ov; bm = om; }
      }
      if (tid < nb) out[rowsS[tid]] = bm;
    }
    __syncthreads();
  }
}

extern "C" void kernel_launch(void* const* d_in, const int* in_sizes, int n_in,
                              void* d_out, int out_size, void* d_ws, size_t ws_size,
                              hipStream_t stream) {
  const float* E = (const float*)d_in[0];
  const float* P = (const float*)d_in[1];
  const int* counts = (const int*)d_in[2];
  const int M = in_sizes[2];            // 1024
  const int Dd = in_sizes[1] / M;       // 256
  const int N = in_sizes[0] / Dd;       // 65536
  int* out = (int*)d_out;

  // workspace: q (4KB) | wcount @4096 | bhi @8192 (512KB) | blo @532480 (512KB) | worklist @1056768
  float* qv = (float*)d_ws;
  int* wcount = (int*)((char*)d_ws + 4096);
  f16x8* bhi = (f16x8*)((char*)d_ws + 8192);
  f16x8* blo = (f16x8*)((char*)d_ws + 8192 + 524288);
  int* wl = (int*)((char*)d_ws + 8192 + 1048576);
  long long cap = ((long long)ws_size - (8192 + 1048576)) / 4;
  if (cap < 0) cap = 0;
  if (cap > N) cap = N;
  int wlcap = (int)cap;

  proto_qnorm_kernel<<<M, 64, 0, stream>>>(P, counts, qv, wcount, M, Dd);
  prep_kernel<<<128, 256, 0, stream>>>(P, qv, bhi, blo);
  screen_kernel<<<N / 128, 512, 0, stream>>>(E, bhi, blo, out, wcount, wl, wlcap);
  rescue_kernel<<<256, 256, 0, stream>>>(E, P, qv, out, wcount, wl, wlcap);
}

// Round 6
// 312.065 us; speedup vs baseline: 1.0608x; 1.0608x over previous
//
#include <hip/hip_runtime.h>
#include <hip/hip_bf16.h>

typedef _Float16 f16x8 __attribute__((ext_vector_type(8)));
typedef float f32x4 __attribute__((ext_vector_type(4)));

#define TAU 1e-4f   // margin below which we rescue in exact f32 (~500 sigma of 3-term split-fp16 noise)

// ---------------- kernel 1: q[m] = (counts[m] > 0) ? 1/||p_m|| : 0 ; zero worklist count ----------------
__global__ __launch_bounds__(64) void proto_qnorm_kernel(
    const float* __restrict__ P, const int* __restrict__ counts,
    float* __restrict__ q, int* __restrict__ wcount, int M, int Dd) {
  if (blockIdx.x == 0 && threadIdx.x == 0) *wcount = 0;
  int m = blockIdx.x;
  int lane = threadIdx.x;
  float s = 0.f;
  for (int k = lane * 4; k < Dd; k += 256) {
    float4 v = *reinterpret_cast<const float4*>(P + (size_t)m * Dd + k);
    s += v.x * v.x + v.y * v.y + v.z * v.z + v.w * v.w;
  }
  for (int off = 32; off > 0; off >>= 1) s += __shfl_xor(s, off, 64);
  if (lane == 0) q[m] = (counts[m] > 0) ? (1.0f / sqrtf(s)) : 0.0f;
}

// ---------------- kernel 1.5: pre-split B-hat = P*q into packed (hi,lo) fp16 fragments ----------------
// Packed so that MFMA B-fragment (p16, kc) for lane L is bhi[((p16*8+kc)<<6) + L]:
// a fragment load = 64 lanes x contiguous 16B = fully coalesced 1KB from L2.
// Element (m, k): p16=m>>4, c=m&15, kc=k>>5, g=(k&31)>>3 -> slot (p16*8+kc)*64 + g*16 + c.
__global__ __launch_bounds__(256) void prep_kernel(
    const float* __restrict__ P, const float* __restrict__ q,
    f16x8* __restrict__ bhi, f16x8* __restrict__ blo) {
  const int id = blockIdx.x * 256 + threadIdx.x;  // 32768 = 1024 m x 32 k-groups
  const int m = id >> 5, kg = id & 31;
  const float qm = q[m];
  const float nanv = __builtin_nanf("");          // masked protos -> NaN (screened out in fold)
  const float* src = P + (size_t)m * 256 + kg * 8;
  float4 v0 = *reinterpret_cast<const float4*>(src);
  float4 v1 = *reinterpret_cast<const float4*>(src + 4);
  float pe[8] = {v0.x, v0.y, v0.z, v0.w, v1.x, v1.y, v1.z, v1.w};
  f16x8 hi, lo;
#pragma unroll
  for (int t = 0; t < 8; ++t) {
    const float ph = (qm > 0.f) ? pe[t] * qm : nanv;
    const _Float16 h = (_Float16)ph;
    hi[t] = h;
    lo[t] = (_Float16)(ph - (float)h);            // exact residual (Sterbenz), then rounded
  }
  const int dst = ((m >> 4) * 8 + (kg >> 2)) * 64 + (kg & 3) * 16 + (m & 15);
  bhi[dst] = hi;
  blo[dst] = lo;
}

// ---------------- kernel 2: split-fp16 MFMA screen, B from global (L2), barrier-free K-loop ----------------
// Block: 512 threads = 8 waves (2 row-groups x 4 col-groups). BM=128 rows.
// A: E split into (hi,lo) fp16, full K=256, resident in 128KB LDS, XOR-swizzled. ONE stage barrier.
// B: pre-split fragments loaded straight from L2 into VGPRs, one-kc-ahead register prefetch.
// dot accumulated as lo*hi + hi*lo + hi*hi chained in one f32 MFMA accumulator.
// __launch_bounds__(512, 1): min 1 block/CU -> 256-VGPR cap. (512,2) capped at 128 VGPRs
// (hipcc min-blocks semantics) and spilled ~380MB/dispatch to scratch in round 5.
__global__ __launch_bounds__(512, 1) void screen_kernel(
    const float* __restrict__ E, const f16x8* __restrict__ bhi,
    const f16x8* __restrict__ blo, int* __restrict__ out,
    int* __restrict__ wcount, int* __restrict__ wl, int wlcap) {
  __shared__ __align__(16) unsigned char ldsA[131072];  // 128 rows x 1024B ([hi 512 | lo 512])

  const int tid = threadIdx.x;
  const int wave = tid >> 6, lane = tid & 63;
  const int rg = wave >> 2, cg = wave & 3;
  const int g = lane >> 4, c = lane & 15;
  const int blockRow = blockIdx.x * 128;

  // ---- stage A once: E[blockRow..+128][0..256) f32 -> (hi,lo) fp16, swizzled ----
  {
    const int row = tid >> 2, qq = tid & 3;  // each thread: 64 consecutive k of one row
    const float* src = E + (size_t)(blockRow + row) * 256 + qq * 64;
    const int rswz = (row & 7) << 4;
#pragma unroll
    for (int o = 0; o < 8; ++o) {
      float4 v0 = *reinterpret_cast<const float4*>(src + o * 8);
      float4 v1 = *reinterpret_cast<const float4*>(src + o * 8 + 4);
      float e[8] = {v0.x, v0.y, v0.z, v0.w, v1.x, v1.y, v1.z, v1.w};
      f16x8 hi, lo;
#pragma unroll
      for (int t = 0; t < 8; ++t) {
        _Float16 h = (_Float16)e[t];
        hi[t] = h;
        lo[t] = (_Float16)(e[t] - (float)h);
      }
      const int base = row * 1024 + (qq * 64 + o * 8) * 2;
      *reinterpret_cast<f16x8*>(ldsA + (base ^ rswz)) = hi;
      *reinterpret_cast<f16x8*>(ldsA + ((base + 512) ^ rswz)) = lo;
    }
  }
  __syncthreads();

  // top-2 state per lane: 16 row-slots (rows = rg*64 + fr*16 + g*4 + reg)
  float v1r[16], v2r[16];
  int i1r[16];
#pragma unroll
  for (int s = 0; s < 16; ++s) { v1r[s] = -INFINITY; v2r[s] = -INFINITY; i1r[s] = 0; }

  const f16x8* bhl = bhi + lane;
  const f16x8* bll = blo + lane;

  // prologue: load B fragments for (pt=0, kc=0)
  f16x8 bhc[4], blc[4];
#pragma unroll
  for (int fc = 0; fc < 4; ++fc) {
    const int fidx = ((cg * 4 + fc) * 8) << 6;   // p16 = 0*16 + cg*4 + fc, kc=0
    bhc[fc] = bhl[fidx];
    blc[fc] = bll[fidx];
  }

  for (int pt = 0; pt < 4; ++pt) {
    f32x4 acc[4][4];
#pragma unroll
    for (int fr = 0; fr < 4; ++fr)
#pragma unroll
      for (int fc = 0; fc < 4; ++fc) acc[fr][fc] = (f32x4){0.f, 0.f, 0.f, 0.f};

#pragma unroll
    for (int kc = 0; kc < 8; ++kc) {
      // ---- prefetch next (pt,kc) B fragments into regs (L2 latency hides under MFMA) ----
      f16x8 bhn[4], bln[4];
      const int t = pt * 8 + kc + 1;
      if (t < 32) {
        const int pn = t >> 3, kn = t & 7;
#pragma unroll
        for (int fc = 0; fc < 4; ++fc) {
          const int fidx = ((pn * 16 + cg * 4 + fc) * 8 + kn) << 6;
          bhn[fc] = bhl[fidx];
          bln[fc] = bll[fidx];
        }
      }
      // ---- A fragments from LDS ----
      f16x8 ah[4], al[4];
#pragma unroll
      for (int fr = 0; fr < 4; ++fr) {
        const int rowA = rg * 64 + fr * 16 + c;
        const int ab = rowA * 1024 + kc * 64 + g * 16;
        const int sw = (rowA & 7) << 4;
        ah[fr] = *reinterpret_cast<const f16x8*>(ldsA + (ab ^ sw));
        al[fr] = *reinterpret_cast<const f16x8*>(ldsA + ((ab + 512) ^ sw));
      }
      // ---- 3-term MFMA ----
#pragma unroll
      for (int fr = 0; fr < 4; ++fr)
#pragma unroll
        for (int fc = 0; fc < 4; ++fc) {
          f32x4 a = acc[fr][fc];
          a = __builtin_amdgcn_mfma_f32_16x16x32_f16(al[fr], bhc[fc], a, 0, 0, 0);
          a = __builtin_amdgcn_mfma_f32_16x16x32_f16(ah[fr], blc[fc], a, 0, 0, 0);
          a = __builtin_amdgcn_mfma_f32_16x16x32_f16(ah[fr], bhc[fc], a, 0, 0, 0);
          acc[fr][fc] = a;
        }
      // ---- rotate prefetch regs ----
#pragma unroll
      for (int fc = 0; fc < 4; ++fc) { bhc[fc] = bhn[fc]; blc[fc] = bln[fc]; }
    }

    // ---- fold this pt's 64 proto-columns into top-2 (full f32, strict > keeps lowest m) ----
#pragma unroll
    for (int fc = 0; fc < 4; ++fc) {
      const int mcol = pt * 256 + cg * 64 + fc * 16 + c;
#pragma unroll
      for (int fr = 0; fr < 4; ++fr)
#pragma unroll
        for (int reg = 0; reg < 4; ++reg) {
          const int s = fr * 4 + reg;
          float v = acc[fr][fc][reg];
          v = (v == v) ? v : -INFINITY;  // NaN guard (masked protos)
          const float nv1 = fmaxf(v1r[s], v);
          v2r[s] = fmaxf(v2r[s], fminf(v1r[s], v));
          i1r[s] = (v > v1r[s]) ? mcol : i1r[s];
          v1r[s] = nv1;
        }
    }
  }

  // ---- cross-lane top-2 merge over the 16 c-lanes sharing each row ----
#pragma unroll
  for (int s = 0; s < 16; ++s) {
#pragma unroll
    for (int off = 1; off <= 8; off <<= 1) {
      const float ov1 = __shfl_xor(v1r[s], off);
      const float ov2 = __shfl_xor(v2r[s], off);
      const int oi1 = __shfl_xor(i1r[s], off);
      const bool take = (ov1 > v1r[s]) || (ov1 == v1r[s] && oi1 < i1r[s]);
      const float nv2 = fmaxf(fmaxf(v2r[s], ov2), fminf(v1r[s], ov1));
      v1r[s] = fmaxf(v1r[s], ov1);
      i1r[s] = take ? oi1 : i1r[s];
      v2r[s] = nv2;
    }
  }

  __syncthreads();  // all waves done with ldsA fragment reads -> reuse for cross-wave merge
  float* mgv1 = reinterpret_cast<float*>(ldsA);          // [128][4]
  float* mgv2 = reinterpret_cast<float*>(ldsA + 2048);   // [128][4]
  int* mgi1 = reinterpret_cast<int*>(ldsA + 4096);       // [128][4]
  if (c == 0) {
#pragma unroll
    for (int s = 0; s < 16; ++s) {
      const int row = rg * 64 + (s >> 2) * 16 + g * 4 + (s & 3);
      mgv1[row * 4 + cg] = v1r[s];
      mgv2[row * 4 + cg] = v2r[s];
      mgi1[row * 4 + cg] = i1r[s];
    }
  }
  __syncthreads();
  if (tid < 128) {
    float v1 = mgv1[tid * 4], v2 = mgv2[tid * 4];
    int i1 = mgi1[tid * 4];
#pragma unroll
    for (int w = 1; w < 4; ++w) {
      const float a1 = mgv1[tid * 4 + w], a2 = mgv2[tid * 4 + w];
      const int ai = mgi1[tid * 4 + w];
      const bool take = (a1 > v1) || (a1 == v1 && ai < i1);
      const float nv2 = fmaxf(fmaxf(v2, a2), fminf(v1, a1));
      v1 = fmaxf(v1, a1);
      i1 = take ? ai : i1;
      v2 = nv2;
    }
    const int grow = blockRow + tid;
    out[grow] = i1;
    const float margin = v1 - v2;
    if (!(margin >= TAU)) {  // NaN-safe: NaN margin -> flagged
      const int p = atomicAdd(wcount, 1);
      if (p < wlcap) wl[p] = grow;
    }
  }
}

// ---------------- kernel 3: exact f32 rescue over the worklist ----------------
// Round-1-identical accumulation per (row, proto): single ascending-k fmaf chain
// (x,y,z,w within each float4), then v = acc*q, ties to the smaller proto index.
__global__ __launch_bounds__(256) void rescue_kernel(
    const float* __restrict__ E, const float* __restrict__ P,
    const float* __restrict__ q, int* __restrict__ out,
    const int* __restrict__ wcount, const int* __restrict__ wl, int wlcap) {
  __shared__ float Elds[8][260];
  __shared__ int rowsS[8];
  __shared__ float wv[8][4];
  __shared__ int wm[8][4];

  const int tid = threadIdx.x;
  const int wave = tid >> 6, lane = tid & 63;
  int total = *wcount;
  if (total > wlcap) total = wlcap;

  for (int b0 = blockIdx.x * 8; b0 < total; b0 += gridDim.x * 8) {
    const int nb = min(8, total - b0);
    __syncthreads();
    if (tid < 8) rowsS[tid] = wl[b0 + (tid < nb ? tid : 0)];
    __syncthreads();
#pragma unroll
    for (int u = 0; u < 2; ++u) {
      const int unit = u * 256 + tid, r = unit >> 6, k4 = unit & 63;
      *reinterpret_cast<float4*>(&Elds[r][k4 * 4]) =
          *reinterpret_cast<const float4*>(E + (size_t)rowsS[r] * 256 + k4 * 4);
    }
    __syncthreads();

    float acc[8][4];  // 8 rows x 4 protos (m = tid + 256*j)
#pragma unroll
    for (int r = 0; r < 8; ++r)
#pragma unroll
      for (int j = 0; j < 4; ++j) acc[r][j] = 0.f;

#pragma unroll 2
    for (int k4 = 0; k4 < 64; ++k4) {
      float4 pv[4];
#pragma unroll
      for (int j = 0; j < 4; ++j)
        pv[j] = *reinterpret_cast<const float4*>(P + (size_t)(tid + 256 * j) * 256 + k4 * 4);
      float4 ev[8];
#pragma unroll
      for (int r = 0; r < 8; ++r) ev[r] = *reinterpret_cast<const float4*>(&Elds[r][k4 * 4]);
#pragma unroll
      for (int r = 0; r < 8; ++r)
#pragma unroll
        for (int j = 0; j < 4; ++j) {
          float a = acc[r][j];
          a = fmaf(pv[j].x, ev[r].x, a);
          a = fmaf(pv[j].y, ev[r].y, a);
          a = fmaf(pv[j].z, ev[r].z, a);
          a = fmaf(pv[j].w, ev[r].w, a);
          acc[r][j] = a;
        }
    }

    float qv[4];
#pragma unroll
    for (int j = 0; j < 4; ++j) qv[j] = q[tid + 256 * j];

#pragma unroll
    for (int r = 0; r < 8; ++r) {
      float bv = -3.0e38f;
      int bm = 0;
#pragma unroll
      for (int j = 0; j < 4; ++j) {  // m ascending -> strict > keeps lowest m
        const float v = (qv[j] > 0.f) ? acc[r][j] * qv[j] : -1.0e30f;
        if (v > bv) { bv = v; bm = tid + 256 * j; }
      }
#pragma unroll
      for (int off = 1; off <= 32; off <<= 1) {
        const float ov = __shfl_xor(bv, off);
        const int om = __shfl_xor(bm, off);
        if (ov > bv || (ov == bv && om < bm)) { bv = ov; bm = om; }
      }
      if (lane == 0) { wv[r][wave] = bv; wm[r][wave] = bm; }
    }
    __syncthreads();
    if (tid < 8) {
      float bv = wv[tid][0];
      int bm = wm[tid][0];
#pragma unroll
      for (int w = 1; w < 4; ++w) {
        const float ov = wv[tid][w];
        const int om = wm[tid][w];
        if (ov > bv || (ov == bv && om < bm)) { bv = ov; bm = om; }
      }
      if (tid < nb) out[rowsS[tid]] = bm;
    }
    __syncthreads();
  }
}

extern "C" void kernel_launch(void* const* d_in, const int* in_sizes, int n_in,
                              void* d_out, int out_size, void* d_ws, size_t ws_size,
                              hipStream_t stream) {
  const float* E = (const float*)d_in[0];
  const float* P = (const float*)d_in[1];
  const int* counts = (const int*)d_in[2];
  const int M = in_sizes[2];            // 1024
  const int Dd = in_sizes[1] / M;       // 256
  const int N = in_sizes[0] / Dd;       // 65536
  int* out = (int*)d_out;

  // workspace: q (4KB) | wcount @4096 | bhi @8192 (512KB) | blo @532480 (512KB) | worklist @1056768
  float* qv = (float*)d_ws;
  int* wcount = (int*)((char*)d_ws + 4096);
  f16x8* bhi = (f16x8*)((char*)d_ws + 8192);
  f16x8* blo = (f16x8*)((char*)d_ws + 8192 + 524288);
  int* wl = (int*)((char*)d_ws + 8192 + 1048576);
  long long cap = ((long long)ws_size - (8192 + 1048576)) / 4;
  if (cap < 0) cap = 0;
  if (cap > N) cap = N;
  int wlcap = (int)cap;

  proto_qnorm_kernel<<<M, 64, 0, stream>>>(P, counts, qv, wcount, M, Dd);
  prep_kernel<<<128, 256, 0, stream>>>(P, qv, bhi, blo);
  screen_kernel<<<N / 128, 512, 0, stream>>>(E, bhi, blo, out, wcount, wl, wlcap);
  rescue_kernel<<<256, 256, 0, stream>>>(E, P, qv, out, wcount, wl, wlcap);
}

// Round 7
// 154.341 us; speedup vs baseline: 2.1448x; 2.0219x over previous
//
#include <hip/hip_runtime.h>
#include <hip/hip_bf16.h>

typedef _Float16 f16x8 __attribute__((ext_vector_type(8)));
typedef float f32x4 __attribute__((ext_vector_type(4)));

#define TAU 4e-3f   // margin below which we rescue in exact f32 (~10 sigma of 2-term fp16 noise)

typedef const __attribute__((address_space(1))) void gas_void;
typedef __attribute__((address_space(3))) void las_void;

__device__ __forceinline__ void gload_lds16(const void* g, void* l) {
  // async global->LDS DMA, 16B/lane; LDS dest = wave-uniform base + lane*16
  __builtin_amdgcn_global_load_lds((gas_void*)g, (las_void*)l, 16, 0, 0);
}

// ---------------- kernel 1: q[m] = (counts[m] > 0) ? 1/||p_m|| : 0 ; zero worklist count ----------------
__global__ __launch_bounds__(64) void proto_qnorm_kernel(
    const float* __restrict__ P, const int* __restrict__ counts,
    float* __restrict__ q, int* __restrict__ wcount, int M, int Dd) {
  if (blockIdx.x == 0 && threadIdx.x == 0) *wcount = 0;
  int m = blockIdx.x;
  int lane = threadIdx.x;
  float s = 0.f;
  for (int k = lane * 4; k < Dd; k += 256) {
    float4 v = *reinterpret_cast<const float4*>(P + (size_t)m * Dd + k);
    s += v.x * v.x + v.y * v.y + v.z * v.z + v.w * v.w;
  }
  for (int off = 32; off > 0; off >>= 1) s += __shfl_xor(s, off, 64);
  if (lane == 0) q[m] = (counts[m] > 0) ? (1.0f / sqrtf(s)) : 0.0f;
}

// ---------------- kernel 1.5: pre-split B-hat = P*q into packed (hi,lo) fp16 fragments ----------------
// Packed so MFMA B-fragment (p16, kc) at lane L sits at byte (p16*8+kc)*1024 + L*16:
// fragment = 64 lanes x contiguous 16B = 1KB chunk (lane-linear -> global_load_lds-ready).
__global__ __launch_bounds__(256) void prep_kernel(
    const float* __restrict__ P, const float* __restrict__ q,
    f16x8* __restrict__ bhi, f16x8* __restrict__ blo) {
  const int id = blockIdx.x * 256 + threadIdx.x;  // 32768 = 1024 m x 32 k-groups
  const int m = id >> 5, kg = id & 31;
  const float qm = q[m];
  const float nanv = __builtin_nanf("");          // masked protos -> NaN (screened out in fold)
  const float* src = P + (size_t)m * 256 + kg * 8;
  float4 v0 = *reinterpret_cast<const float4*>(src);
  float4 v1 = *reinterpret_cast<const float4*>(src + 4);
  float pe[8] = {v0.x, v0.y, v0.z, v0.w, v1.x, v1.y, v1.z, v1.w};
  f16x8 hi, lo;
#pragma unroll
  for (int t = 0; t < 8; ++t) {
    const float ph = (qm > 0.f) ? pe[t] * qm : nanv;
    const _Float16 h = (_Float16)ph;
    hi[t] = h;
    lo[t] = (_Float16)(ph - (float)h);            // exact residual (Sterbenz), then rounded
  }
  const int dst = ((m >> 4) * 8 + (kg >> 2)) * 64 + (kg & 3) * 16 + (m & 15);
  bhi[dst] = hi;
  blo[dst] = lo;
}

// ---------------- kernel 2: 2-term split-fp16 MFMA screen ----------------
// Block: 512 threads = 8 waves (2 row-groups x 4 col-groups). BM=128 rows, wave tile 64x64.
// A: E hi-only fp16, full K=256, resident in 64KB LDS, XOR-swizzled (staged once).
// B: pre-split packed fragments DMA'd per (pt,kc) step into a 2x32KB LDS double buffer
//    via global_load_lds (no VGPR round-trip, no conversion, conflict-free reads).
// dot = ah*bh + ah*bl chained in one f32 MFMA accumulator (B good to 22 bits; A fp16).
__global__ __launch_bounds__(512) void screen_kernel(
    const float* __restrict__ E, const f16x8* __restrict__ bhi,
    const f16x8* __restrict__ blo, int* __restrict__ out,
    int* __restrict__ wcount, int* __restrict__ wl, int wlcap) {
  __shared__ __align__(16) unsigned char ldsA[65536];   // 128 rows x 512B (hi fp16, K=256)
  __shared__ __align__(16) unsigned char ldsB[65536];   // 2 bufs x [hi 16KB | lo 16KB]

  const int tid = threadIdx.x;
  const int wave = tid >> 6, lane = tid & 63;
  const int rg = wave >> 2, cg = wave & 3;
  const int g = lane >> 4, c = lane & 15;
  const int blockRow = blockIdx.x * 128;
  const char* bhiB = (const char*)bhi;
  const char* bloB = (const char*)blo;

  // ---- stage A once: E[blockRow..+128][0..256) f32 -> hi fp16, swizzled ----
  {
    const int row = tid >> 2, qq = tid & 3;  // each thread: 64 consecutive k of one row
    const float* src = E + (size_t)(blockRow + row) * 256 + qq * 64;
    const int rswz = (row & 7) << 4;
#pragma unroll
    for (int o = 0; o < 8; ++o) {
      float4 v0 = *reinterpret_cast<const float4*>(src + o * 8);
      float4 v1 = *reinterpret_cast<const float4*>(src + o * 8 + 4);
      float e[8] = {v0.x, v0.y, v0.z, v0.w, v1.x, v1.y, v1.z, v1.w};
      f16x8 hi;
#pragma unroll
      for (int t = 0; t < 8; ++t) hi[t] = (_Float16)e[t];
      const int byte = (row * 512 + (qq * 64 + o * 8) * 2) ^ rswz;
      *reinterpret_cast<f16x8*>(ldsA + byte) = hi;
    }
  }

  // ---- B stage helper: DMA step t=(pt,kc) into buffer b (each wave: 2 hi + 2 lo chunks) ----
  const int chunk = wave * 2;
  auto stageB = [&](int b, int t) {
    const int ptn = t >> 3, kcn = t & 7;
    const size_t src = (size_t)((ptn * 16 + chunk) * 8 + kcn) * 1024 + (size_t)lane * 16;
    char* dstb = (char*)ldsB + b * 32768 + chunk * 1024;
    gload_lds16(bhiB + src, dstb);
    gload_lds16(bhiB + src + 8192, dstb + 1024);       // chunk+1: src stride 8KB
    gload_lds16(bloB + src, dstb + 16384);
    gload_lds16(bloB + src + 8192, dstb + 16384 + 1024);
  };

  stageB(0, 0);
  __syncthreads();  // A staged + first B landed

  // top-2 state per lane: 16 row-slots (rows = rg*64 + fr*16 + g*4 + reg)
  float v1r[16], v2r[16];
  int i1r[16];
#pragma unroll
  for (int s = 0; s < 16; ++s) { v1r[s] = -INFINITY; v2r[s] = -INFINITY; i1r[s] = 0; }

  int buf = 0;
  for (int pt = 0; pt < 4; ++pt) {
    f32x4 acc[4][4];
#pragma unroll
    for (int fr = 0; fr < 4; ++fr)
#pragma unroll
      for (int fc = 0; fc < 4; ++fc) acc[fr][fc] = (f32x4){0.f, 0.f, 0.f, 0.f};

    for (int kc = 0; kc < 8; ++kc) {
      const int t = pt * 8 + kc;
      if (t < 31) stageB(buf ^ 1, t + 1);   // DMA next step; hides under MFMA below

      // ---- A fragments (hi) from LDS ----
      f16x8 ah[4];
#pragma unroll
      for (int fr = 0; fr < 4; ++fr) {
        const int rowA = rg * 64 + fr * 16 + c;
        const int ab = (rowA * 512 + kc * 64 + g * 16) ^ ((rowA & 7) << 4);
        ah[fr] = *reinterpret_cast<const f16x8*>(ldsA + ab);
      }
      const char* bbase = (const char*)ldsB + buf * 32768 + (cg * 4) * 1024 + (size_t)lane * 16;
      // ---- term 1: ah * bh ----
      {
        f16x8 bf[4];
#pragma unroll
        for (int fc = 0; fc < 4; ++fc) bf[fc] = *reinterpret_cast<const f16x8*>(bbase + fc * 1024);
#pragma unroll
        for (int fr = 0; fr < 4; ++fr)
#pragma unroll
          for (int fc = 0; fc < 4; ++fc)
            acc[fr][fc] = __builtin_amdgcn_mfma_f32_16x16x32_f16(ah[fr], bf[fc], acc[fr][fc], 0, 0, 0);
      }
      // ---- term 2: ah * bl ----
      {
        f16x8 bf[4];
#pragma unroll
        for (int fc = 0; fc < 4; ++fc) bf[fc] = *reinterpret_cast<const f16x8*>(bbase + 16384 + fc * 1024);
#pragma unroll
        for (int fr = 0; fr < 4; ++fr)
#pragma unroll
          for (int fc = 0; fc < 4; ++fc)
            acc[fr][fc] = __builtin_amdgcn_mfma_f32_16x16x32_f16(ah[fr], bf[fc], acc[fr][fc], 0, 0, 0);
      }
      __syncthreads();  // drains the DMA (vmcnt) + all waves done reading buf
      buf ^= 1;
    }

    // ---- fold this pt's 64 proto-columns into top-2 (full f32, strict > keeps lowest m) ----
#pragma unroll
    for (int fc = 0; fc < 4; ++fc) {
      const int mcol = pt * 256 + cg * 64 + fc * 16 + c;
#pragma unroll
      for (int fr = 0; fr < 4; ++fr)
#pragma unroll
        for (int reg = 0; reg < 4; ++reg) {
          const int s = fr * 4 + reg;
          float v = acc[fr][fc][reg];
          v = (v == v) ? v : -INFINITY;  // NaN guard (masked protos)
          const float nv1 = fmaxf(v1r[s], v);
          v2r[s] = fmaxf(v2r[s], fminf(v1r[s], v));
          i1r[s] = (v > v1r[s]) ? mcol : i1r[s];
          v1r[s] = nv1;
        }
    }
  }

  // ---- cross-lane top-2 merge over the 16 c-lanes sharing each row ----
#pragma unroll
  for (int s = 0; s < 16; ++s) {
#pragma unroll
    for (int off = 1; off <= 8; off <<= 1) {
      const float ov1 = __shfl_xor(v1r[s], off);
      const float ov2 = __shfl_xor(v2r[s], off);
      const int oi1 = __shfl_xor(i1r[s], off);
      const bool take = (ov1 > v1r[s]) || (ov1 == v1r[s] && oi1 < i1r[s]);
      const float nv2 = fmaxf(fmaxf(v2r[s], ov2), fminf(v1r[s], ov1));
      v1r[s] = fmaxf(v1r[s], ov1);
      i1r[s] = take ? oi1 : i1r[s];
      v2r[s] = nv2;
    }
  }

  __syncthreads();  // all LDS use done -> reuse ldsA for cross-wave merge
  float* mgv1 = reinterpret_cast<float*>(ldsA);          // [128][4]
  float* mgv2 = reinterpret_cast<float*>(ldsA + 2048);   // [128][4]
  int* mgi1 = reinterpret_cast<int*>(ldsA + 4096);       // [128][4]
  if (c == 0) {
#pragma unroll
    for (int s = 0; s < 16; ++s) {
      const int row = rg * 64 + (s >> 2) * 16 + g * 4 + (s & 3);
      mgv1[row * 4 + cg] = v1r[s];
      mgv2[row * 4 + cg] = v2r[s];
      mgi1[row * 4 + cg] = i1r[s];
    }
  }
  __syncthreads();
  if (tid < 128) {
    float v1 = mgv1[tid * 4], v2 = mgv2[tid * 4];
    int i1 = mgi1[tid * 4];
#pragma unroll
    for (int w = 1; w < 4; ++w) {
      const float a1 = mgv1[tid * 4 + w], a2 = mgv2[tid * 4 + w];
      const int ai = mgi1[tid * 4 + w];
      const bool take = (a1 > v1) || (a1 == v1 && ai < i1);
      const float nv2 = fmaxf(fmaxf(v2, a2), fminf(v1, a1));
      v1 = fmaxf(v1, a1);
      i1 = take ? ai : i1;
      v2 = nv2;
    }
    const int grow = blockRow + tid;
    out[grow] = i1;
    const float margin = v1 - v2;
    if (!(margin >= TAU)) {  // NaN-safe: NaN margin -> flagged
      const int p = atomicAdd(wcount, 1);
      if (p < wlcap) wl[p] = grow;
    }
  }
}

// ---------------- kernel 3: exact f32 rescue over the worklist ----------------
// Round-1-identical accumulation per (row, proto): single ascending-k fmaf chain
// (x,y,z,w within each float4), then v = acc*q, ties to the smaller proto index.
__global__ __launch_bounds__(256) void rescue_kernel(
    const float* __restrict__ E, const float* __restrict__ P,
    const float* __restrict__ q, int* __restrict__ out,
    const int* __restrict__ wcount, const int* __restrict__ wl, int wlcap) {
  __shared__ float Elds[8][260];
  __shared__ int rowsS[8];
  __shared__ float wv[8][4];
  __shared__ int wm[8][4];

  const int tid = threadIdx.x;
  const int wave = tid >> 6, lane = tid & 63;
  int total = *wcount;
  if (total > wlcap) total = wlcap;

  for (int b0 = blockIdx.x * 8; b0 < total; b0 += gridDim.x * 8) {
    const int nb = min(8, total - b0);
    __syncthreads();
    if (tid < 8) rowsS[tid] = wl[b0 + (tid < nb ? tid : 0)];
    __syncthreads();
#pragma unroll
    for (int u = 0; u < 2; ++u) {
      const int unit = u * 256 + tid, r = unit >> 6, k4 = unit & 63;
      *reinterpret_cast<float4*>(&Elds[r][k4 * 4]) =
          *reinterpret_cast<const float4*>(E + (size_t)rowsS[r] * 256 + k4 * 4);
    }
    __syncthreads();

    float acc[8][4];  // 8 rows x 4 protos (m = tid + 256*j)
#pragma unroll
    for (int r = 0; r < 8; ++r)
#pragma unroll
      for (int j = 0; j < 4; ++j) acc[r][j] = 0.f;

#pragma unroll 2
    for (int k4 = 0; k4 < 64; ++k4) {
      float4 pv[4];
#pragma unroll
      for (int j = 0; j < 4; ++j)
        pv[j] = *reinterpret_cast<const float4*>(P + (size_t)(tid + 256 * j) * 256 + k4 * 4);
      float4 ev[8];
#pragma unroll
      for (int r = 0; r < 8; ++r) ev[r] = *reinterpret_cast<const float4*>(&Elds[r][k4 * 4]);
#pragma unroll
      for (int r = 0; r < 8; ++r)
#pragma unroll
        for (int j = 0; j < 4; ++j) {
          float a = acc[r][j];
          a = fmaf(pv[j].x, ev[r].x, a);
          a = fmaf(pv[j].y, ev[r].y, a);
          a = fmaf(pv[j].z, ev[r].z, a);
          a = fmaf(pv[j].w, ev[r].w, a);
          acc[r][j] = a;
        }
    }

    float qv[4];
#pragma unroll
    for (int j = 0; j < 4; ++j) qv[j] = q[tid + 256 * j];

#pragma unroll
    for (int r = 0; r < 8; ++r) {
      float bv = -3.0e38f;
      int bm = 0;
#pragma unroll
      for (int j = 0; j < 4; ++j) {  // m ascending -> strict > keeps lowest m
        const float v = (qv[j] > 0.f) ? acc[r][j] * qv[j] : -1.0e30f;
        if (v > bv) { bv = v; bm = tid + 256 * j; }
      }
#pragma unroll
      for (int off = 1; off <= 32; off <<= 1) {
        const float ov = __shfl_xor(bv, off);
        const int om = __shfl_xor(bm, off);
        if (ov > bv || (ov == bv && om < bm)) { bv = ov; bm = om; }
      }
      if (lane == 0) { wv[r][wave] = bv; wm[r][wave] = bm; }
    }
    __syncthreads();
    if (tid < 8) {
      float bv = wv[tid][0];
      int bm = wm[tid][0];
#pragma unroll
      for (int w = 1; w < 4; ++w) {
        const float ov = wv[tid][w];
        const int om = wm[tid][w];
        if (ov > bv || (ov == bv && om < bm)) { bv = ov; bm = om; }
      }
      if (tid < nb) out[rowsS[tid]] = bm;
    }
    __syncthreads();
  }
}

extern "C" void kernel_launch(void* const* d_in, const int* in_sizes, int n_in,
                              void* d_out, int out_size, void* d_ws, size_t ws_size,
                              hipStream_t stream) {
  const float* E = (const float*)d_in[0];
  const float* P = (const float*)d_in[1];
  const int* counts = (const int*)d_in[2];
  const int M = in_sizes[2];            // 1024
  const int Dd = in_sizes[1] / M;       // 256
  const int N = in_sizes[0] / Dd;       // 65536
  int* out = (int*)d_out;

  // workspace: q (4KB) | wcount @4096 | bhi @8192 (512KB) | blo @532480 (512KB) | worklist @1056768
  float* qv = (float*)d_ws;
  int* wcount = (int*)((char*)d_ws + 4096);
  f16x8* bhi = (f16x8*)((char*)d_ws + 8192);
  f16x8* blo = (f16x8*)((char*)d_ws + 8192 + 524288);
  int* wl = (int*)((char*)d_ws + 8192 + 1048576);
  long long cap = ((long long)ws_size - (8192 + 1048576)) / 4;
  if (cap < 0) cap = 0;
  if (cap > N) cap = N;
  int wlcap = (int)cap;

  proto_qnorm_kernel<<<M, 64, 0, stream>>>(P, counts, qv, wcount, M, Dd);
  prep_kernel<<<128, 256, 0, stream>>>(P, qv, bhi, blo);
  screen_kernel<<<N / 128, 512, 0, stream>>>(E, bhi, blo, out, wcount, wl, wlcap);
  rescue_kernel<<<256, 256, 0, stream>>>(E, P, qv, out, wcount, wl, wlcap);
}